// Round 4
// baseline (29.325 us; speedup 1.0000x reference)
//
#include <hip/hip_runtime.h>
#include <hip/hip_bf16.h>

#define TD 512    // teacher dim (K)
#define SD 128    // student dim (N)
#define NT 8      // n tasks
#define BATCH 16384

typedef float f32x4 __attribute__((ext_vector_type(4)));
typedef short s16x8 __attribute__((ext_vector_type(8)));

__device__ inline unsigned short f2bf(float f) {
    __hip_bfloat16 h = __float2bfloat16(f);   // RNE; compiler packs to v_cvt_pk_bf16_f32
    return __builtin_bit_cast(unsigned short, h);
}

// Transpose W [512][128] f32 -> Wt [128][512] bf16 (in d_ws).
// tid = n*512 + k: writes coalesced; scattered reads absorbed by L2 (W = 256 KB).
__global__ __launch_bounds__(256) void wprep_kernel(
    const float* __restrict__ W, unsigned short* __restrict__ Wt) {
    int tid = blockIdx.x * 256 + threadIdx.x;   // 0..65535
    int n = tid >> 9;
    int k = tid & 511;
    Wt[tid] = f2bf(W[k * SD + n]);
}

// Main kernel: block = 16 batch rows, 4 waves split K (128 each).
// B-fragments straight from L2-resident Wt; no barrier in compute loop;
// one LDS reduce at the end. Grid 1024 x 256.
__global__ __launch_bounds__(256) void fused_kernel(
    const float* __restrict__ emb,            // [500000][512]
    const float* __restrict__ clogits,        // [500000][8]
    const unsigned short* __restrict__ Wt,    // [128][512] bf16
    const int* __restrict__ slot,             // [16384]
    const int* __restrict__ hit,              // [16384] int32 bool
    float* __restrict__ feats_out,            // [16384][128]
    float* __restrict__ logits_out)           // [16384][8]
{
    __shared__ float red[4][16][SD];          // 32 KiB split-K partials

    const int tid = threadIdx.x;
    const int m0 = blockIdx.x * 16;

    // ---- logits: 16 rows x 8 tasks, threads 0..127 ----
    if (tid < 128) {
        const int row = m0 + (tid >> 3);
        const int j = tid & 7;
        float v = 0.f;
        if (hit[row]) v = clogits[(long)slot[row] * NT + j];
        logits_out[(long)row * NT + j] = v;
    }

    const int w    = tid >> 6;      // wave = K-slice index
    const int lane = tid & 63;
    const int lr   = lane & 15;     // A row / B col / D col within tile
    const int kb   = lane >> 4;     // k-octet 0..3
    const int kbase = w * 128;      // this wave's K range

    const int arow_idx = m0 + lr;
    const long myslot = slot[arow_idx];
    const bool myhit = hit[arow_idx] != 0;
    const float* arow = emb + myslot * (long)TD + kbase;

    // ---- hoist all A-gather loads for this wave's K-slice ----
    f32x4 af[8];
    if (myhit) {
        #pragma unroll
        for (int ks = 0; ks < 4; ++ks) {
            const int ko = ks * 32 + kb * 8;
            af[2 * ks]     = *(const f32x4*)(arow + ko);
            af[2 * ks + 1] = *(const f32x4*)(arow + ko + 4);
        }
    }

    f32x4 acc[8];
    #pragma unroll
    for (int t = 0; t < 8; ++t) acc[t] = (f32x4){0.f, 0.f, 0.f, 0.f};

    const unsigned short* wtb = Wt + kbase + kb * 8;

    #pragma unroll
    for (int ks = 0; ks < 4; ++ks) {
        s16x8 a;
        if (myhit) {
            const f32x4 f0 = af[2 * ks];
            const f32x4 f1 = af[2 * ks + 1];
            #pragma unroll
            for (int j = 0; j < 4; ++j) a[j]     = (short)f2bf(f0[j]);
            #pragma unroll
            for (int j = 0; j < 4; ++j) a[4 + j] = (short)f2bf(f1[j]);
        } else {
            a = (s16x8){0, 0, 0, 0, 0, 0, 0, 0};
        }
        #pragma unroll
        for (int t = 0; t < 8; ++t) {
            const s16x8 b = *(const s16x8*)(wtb + (t * 16 + lr) * TD + ks * 32);
            acc[t] = __builtin_amdgcn_mfma_f32_16x16x32_bf16(a, b, acc[t], 0, 0, 0);
        }
    }

    // ---- write K-partials to LDS: D elem (row=kb*4+i, col=t*16+lr) ----
    #pragma unroll
    for (int t = 0; t < 8; ++t) {
        #pragma unroll
        for (int i = 0; i < 4; ++i)
            red[w][kb * 4 + i][t * 16 + lr] = acc[t][i];
    }
    __syncthreads();

    // ---- 4-way sum + store: thread -> (row = tid>>4, 8 cols at (tid&15)*8) ----
    const int row = tid >> 4;
    const int cg  = (tid & 15) * 8;
    f32x4 s0 = (f32x4){0.f, 0.f, 0.f, 0.f};
    f32x4 s1 = (f32x4){0.f, 0.f, 0.f, 0.f};
    #pragma unroll
    for (int w2 = 0; w2 < 4; ++w2) {
        s0 += *(const f32x4*)&red[w2][row][cg];
        s1 += *(const f32x4*)&red[w2][row][cg + 4];
    }
    float* o = feats_out + (long)(m0 + row) * SD + cg;
    *(f32x4*)o       = s0;
    *(f32x4*)(o + 4) = s1;
}

extern "C" void kernel_launch(void* const* d_in, const int* in_sizes, int n_in,
                              void* d_out, int out_size, void* d_ws, size_t ws_size,
                              hipStream_t stream) {
    const float* cache_emb    = (const float*)d_in[0];
    const float* cache_logits = (const float*)d_in[1];
    const float* W            = (const float*)d_in[2];
    const int*   slot_idx     = (const int*)d_in[3];
    const int*   hitm         = (const int*)d_in[4];

    float* feats_out  = (float*)d_out;                       // 16384*128
    float* logits_out = (float*)d_out + (long)BATCH * SD;    // 16384*8

    unsigned short* Wt = (unsigned short*)d_ws;              // 128*512 bf16 = 128 KiB

    wprep_kernel<<<256, 256, 0, stream>>>(W, Wt);
    fused_kernel<<<BATCH / 16, 256, 0, stream>>>(cache_emb, cache_logits, Wt,
                                                 slot_idx, hitm,
                                                 feats_out, logits_out);
}

// Round 5
// 21.911 us; speedup vs baseline: 1.3384x; 1.3384x over previous
//
#include <hip/hip_runtime.h>
#include <hip/hip_bf16.h>

#define TD 512    // teacher dim (K)
#define SD 128    // student dim (N)
#define NT 8      // n tasks
#define BATCH 16384

typedef float f32x2 __attribute__((ext_vector_type(2)));
typedef float f32x4 __attribute__((ext_vector_type(4)));
typedef short s16x8 __attribute__((ext_vector_type(8)));
typedef unsigned short u16;

__device__ inline u16 f2bf(float f) {
    return __builtin_bit_cast(u16, __float2bfloat16(f));   // RNE, cvt_pk-packable
}

// grid = 512 blocks (256 row-groups x 2 n-halves), 256 threads (4 waves).
// Block: 64 rows x 64 cols, full K=512. Wave: 16 rows x 64 cols.
// LDS: W n-half as bf16 in 16B units [oct = k>>3 (64)][nn (64)], unit = 8
// consecutive k of one column. B-fragment ds_read_b128: 16 contiguous lanes
// x 16 B -> conflict-free. Staged ONCE per block; no barriers after.
__global__ __launch_bounds__(256, 2) void fused_kernel(
    const float* __restrict__ emb,            // [500000][512]
    const float* __restrict__ clogits,        // [500000][8]
    const float* __restrict__ W,              // [512][128]
    const int* __restrict__ slot,             // [16384]
    const int* __restrict__ hit,              // [16384] int32 bool
    float* __restrict__ feats_out,            // [16384][128]
    float* __restrict__ logits_out)           // [16384][8]
{
    __shared__ u16 Wt[64 * 64 * 8];           // 64 KiB

    const int tid = threadIdx.x;
    const int rg = blockIdx.x & 255;          // row-group (64 rows)
    const int h  = blockIdx.x >> 8;           // n-half; b and b+256 share rows
    const int m0 = rg * 64;
    const int nb = h * 64;

    // ---- issue ALL staging loads first (oldest in vmem queue) ----
    // 512 k x 64 n f32 = 32768 elems; 64 x f32x2 per thread, coalesced.
    f32x2 wv[64];
    #pragma unroll
    for (int it = 0; it < 64; ++it) {
        const int flat = it * 512 + tid * 2;
        const int k  = flat >> 6;
        const int nn = flat & 63;
        wv[it] = *(const f32x2*)(W + (long)k * SD + nb + nn);
    }

    // ---- logits (h==0 blocks only): newer loads, overlap staging ----
    if (h == 0) {
        #pragma unroll
        for (int i = 0; i < 2; ++i) {
            const int e = i * 256 + tid;
            const int row = m0 + (e >> 3);
            const int j = e & 7;
            float v = 0.f;
            if (hit[row]) v = clogits[(long)slot[row] * NT + j];
            logits_out[(long)row * NT + j] = v;
        }
    }

    // ---- convert + write staging to LDS ----
    #pragma unroll
    for (int it = 0; it < 64; ++it) {
        const int flat = it * 512 + tid * 2;
        const int k  = flat >> 6;
        const int nn = flat & 63;
        const int base = ((k >> 3) * 64 + nn) * 8 + (k & 7);
        Wt[base]     = f2bf(wv[it][0]);
        Wt[base + 8] = f2bf(wv[it][1]);
    }
    __syncthreads();

    // ---- per-lane GEMM identity ----
    const int w = tid >> 6, lane = tid & 63;
    const int lr = lane & 15;     // A row / B col / D col within 16-tile
    const int kb = lane >> 4;     // k-octet 0..3
    const int arow = m0 + w * 16 + lr;
    const long slotv = slot[arow];
    const bool hitv = hit[arow] != 0;
    const float* ap = emb + slotv * (long)TD;

    // ---- issue ALL gather loads (512 B/lane in flight) ----
    f32x4 af[32];
    if (hitv) {
        #pragma unroll
        for (int ks = 0; ks < 16; ++ks) {
            const int ko = ks * 32 + kb * 8;
            af[2 * ks]     = *(const f32x4*)(ap + ko);
            af[2 * ks + 1] = *(const f32x4*)(ap + ko + 4);
        }
    }

    f32x4 acc[4];
    #pragma unroll
    for (int t = 0; t < 4; ++t) acc[t] = (f32x4){0.f, 0.f, 0.f, 0.f};

    // ---- barrier-free MFMA loop ----
    #pragma unroll
    for (int ks = 0; ks < 16; ++ks) {
        s16x8 a;
        if (hitv) {
            const f32x4 f0 = af[2 * ks], f1 = af[2 * ks + 1];
            #pragma unroll
            for (int j = 0; j < 4; ++j) a[j]     = (short)f2bf(f0[j]);
            #pragma unroll
            for (int j = 0; j < 4; ++j) a[4 + j] = (short)f2bf(f1[j]);
        } else {
            a = (s16x8){0, 0, 0, 0, 0, 0, 0, 0};
        }
        #pragma unroll
        for (int t = 0; t < 4; ++t) {
            const s16x8 b = *(const s16x8*)&Wt[((ks * 4 + kb) * 64 + t * 16 + lr) * 8];
            acc[t] = __builtin_amdgcn_mfma_f32_16x16x32_bf16(a, b, acc[t], 0, 0, 0);
        }
    }

    // ---- store: D row = kb*4+i, col = t*16+lr ----
    #pragma unroll
    for (int t = 0; t < 4; ++t) {
        #pragma unroll
        for (int i = 0; i < 4; ++i) {
            feats_out[(long)(m0 + w * 16 + kb * 4 + i) * SD + nb + t * 16 + lr]
                = acc[t][i];
        }
    }
}

extern "C" void kernel_launch(void* const* d_in, const int* in_sizes, int n_in,
                              void* d_out, int out_size, void* d_ws, size_t ws_size,
                              hipStream_t stream) {
    const float* cache_emb    = (const float*)d_in[0];
    const float* cache_logits = (const float*)d_in[1];
    const float* W            = (const float*)d_in[2];
    const int*   slot_idx     = (const int*)d_in[3];
    const int*   hitm         = (const int*)d_in[4];

    float* feats_out  = (float*)d_out;                       // 16384*128
    float* logits_out = (float*)d_out + (long)BATCH * SD;    // 16384*8

    fused_kernel<<<512, 256, 0, stream>>>(cache_emb, cache_logits, W,
                                          slot_idx, hitm,
                                          feats_out, logits_out);
}

// Round 6
// 21.694 us; speedup vs baseline: 1.3518x; 1.0100x over previous
//
#include <hip/hip_runtime.h>
#include <hip/hip_bf16.h>

#define TD 512
#define SD 128
#define NT 8
#define BATCH 16384

typedef float f32x2 __attribute__((ext_vector_type(2)));
typedef float f32x4 __attribute__((ext_vector_type(4)));
typedef short s16x8 __attribute__((ext_vector_type(8)));
typedef unsigned short u16;

__device__ __forceinline__ u16 f2bf(float f) {
    return __builtin_bit_cast(u16, __float2bfloat16(f));   // RNE
}

__device__ __forceinline__ void glds16(const void* g, void* l) {
    __builtin_amdgcn_global_load_lds(
        (const __attribute__((address_space(1))) unsigned int*)g,
        (__attribute__((address_space(3))) unsigned int*)l, 16, 0, 0);
}

// wprep: W [512][128] f32 -> Wt [128][512] bf16 (d_ws). Reads stride-512B
// (L2-absorbed, W=256KB), writes perfectly coalesced 16B.
__global__ __launch_bounds__(256) void wprep_kernel(
    const float* __restrict__ W, u16* __restrict__ Wt) {
    const int gid = blockIdx.x * 256 + threadIdx.x;  // 0..8191
    const int n = gid >> 6;
    const int ko = (gid & 63) * 8;
    u16 v[8];
    #pragma unroll
    for (int i = 0; i < 8; ++i) v[i] = f2bf(W[(ko + i) * SD + n]);
    *(s16x8*)(Wt + n * TD + ko) = *(const s16x8*)v;
}

// Main: 256 blocks x 256 thr (4 waves). Block = 64 rows x 128 cols, K=512 in
// 4 chunks of 128. Wt chunk -> LDS via global_load_lds (4 buffers, no reuse).
// A gathered to regs 2 chunks ahead. Counted vmcnt + raw s_barrier (T3+T4).
__global__ __launch_bounds__(256, 1) void fused_kernel(
    const float* __restrict__ emb,            // [500000][512]
    const float* __restrict__ clogits,        // [500000][8]
    const u16* __restrict__ Wt,               // [128][512] bf16
    const int* __restrict__ slot,             // [16384]
    const int* __restrict__ hit,              // [16384] int32 bool
    float* __restrict__ feats_out,            // [16384][128]
    float* __restrict__ logits_out)           // [16384][8]
{
    __shared__ __align__(16) char lds[4 * 32768];   // 128 KiB

    const int tid  = threadIdx.x;
    const int wv   = tid >> 6;
    const int lane = tid & 63;
    const int lr   = lane & 15;     // A row / B col / D col in 16-tile
    const int kb   = lane >> 4;     // k-octet 0..3
    const int m0   = blockIdx.x * 64;

    const int arow = m0 + wv * 16 + lr;
    const int hitv = hit[arow];
    const long slotv = slot[arow];
    const float* ap = emb + (hitv ? slotv : 0) * (long)TD;

    f32x4 af0[8], af1[8], af2[8];
    f32x4 acc[8];
    #pragma unroll
    for (int t = 0; t < 8; ++t) acc[t] = (f32x4){0.f, 0.f, 0.f, 0.f};

    // One batch = 8 glds (32KB Wt chunk, all threads) + 8 A-loads (128B/lane).
    // LDS unit u = oct*128 + n (16B each); thread covers u = tid + 256*i.
#define ISSUE(c, AF)                                                         \
    {                                                                        \
        const int koff = (c) * 128;                                          \
        _Pragma("unroll")                                                    \
        for (int i = 0; i < 8; ++i) {                                        \
            const int u = tid + 256 * i;                                     \
            glds16(Wt + (u & 127) * TD + koff + (u >> 7) * 8,                \
                   lds + (c) * 32768 + (wv * 64 + 256 * i) * 16);            \
        }                                                                    \
        _Pragma("unroll")                                                    \
        for (int ks = 0; ks < 4; ++ks) {                                     \
            const float* p = ap + koff + ks * 32 + kb * 8;                   \
            AF[2 * ks]     = *(const f32x4*)p;                               \
            AF[2 * ks + 1] = *(const f32x4*)(p + 4);                         \
        }                                                                    \
    }

#define COMPUTE(c, AF)                                                       \
    {                                                                        \
        _Pragma("unroll")                                                    \
        for (int ks = 0; ks < 4; ++ks) {                                     \
            s16x8 a;                                                         \
            const f32x4 f0 = AF[2 * ks], f1 = AF[2 * ks + 1];                \
            _Pragma("unroll")                                                \
            for (int j = 0; j < 4; ++j) a[j]     = (short)f2bf(f0[j]);       \
            _Pragma("unroll")                                                \
            for (int j = 0; j < 4; ++j) a[4 + j] = (short)f2bf(f1[j]);       \
            if (!hitv) a = (s16x8){0, 0, 0, 0, 0, 0, 0, 0};                  \
            _Pragma("unroll")                                                \
            for (int t = 0; t < 8; ++t) {                                    \
                const s16x8 b = *(const s16x8*)(lds + (c) * 32768 +          \
                    ((((ks * 4 + kb) * 128) + t * 16 + lr) * 16));           \
                acc[t] = __builtin_amdgcn_mfma_f32_16x16x32_bf16(            \
                             a, b, acc[t], 0, 0, 0);                         \
            }                                                                \
        }                                                                    \
    }

#define WAITBAR(N)                                                           \
    asm volatile("s_waitcnt vmcnt(" #N ")" ::: "memory");                    \
    __builtin_amdgcn_sched_barrier(0);                                       \
    __builtin_amdgcn_s_barrier();                                            \
    __builtin_amdgcn_sched_barrier(0);

    ISSUE(0, af0);
    ISSUE(1, af1);

    ISSUE(2, af2);          // c = 0
    WAITBAR(32)             // batch0 done (batch1+batch2 = 32 newest stay)
    COMPUTE(0, af0);

    ISSUE(3, af0);          // c = 1
    WAITBAR(32)             // batch1 done
    COMPUTE(1, af1);

    WAITBAR(16)             // c = 2: batch2 done (batch3 outstanding)
    COMPUTE(2, af2);

    WAITBAR(0)              // c = 3: all done
    COMPUTE(3, af0);

#undef ISSUE
#undef COMPUTE
#undef WAITBAR

    // ---- feats store: D row = kb*4+i, col = t*16+lr ----
    #pragma unroll
    for (int t = 0; t < 8; ++t) {
        #pragma unroll
        for (int i = 0; i < 4; ++i)
            feats_out[(long)(m0 + wv * 16 + kb * 4 + i) * SD + t * 16 + lr]
                = acc[t][i];
    }

    // ---- logits: 64 rows x 8, f32x2 per thread, coalesced ----
    {
        const int row = m0 + (tid >> 2);
        const int j = (tid & 3) * 2;
        f32x2 v = (f32x2){0.f, 0.f};
        if (hit[row]) v = *(const f32x2*)(clogits + (long)slot[row] * NT + j);
        *(f32x2*)(logits_out + (long)row * NT + j) = v;
    }
}

extern "C" void kernel_launch(void* const* d_in, const int* in_sizes, int n_in,
                              void* d_out, int out_size, void* d_ws, size_t ws_size,
                              hipStream_t stream) {
    const float* cache_emb    = (const float*)d_in[0];
    const float* cache_logits = (const float*)d_in[1];
    const float* W            = (const float*)d_in[2];
    const int*   slot_idx     = (const int*)d_in[3];
    const int*   hitm         = (const int*)d_in[4];

    float* feats_out  = (float*)d_out;                       // 16384*128
    float* logits_out = (float*)d_out + (long)BATCH * SD;    // 16384*8

    u16* Wt = (u16*)d_ws;                                    // 128 KiB

    wprep_kernel<<<32, 256, 0, stream>>>(W, Wt);
    fused_kernel<<<BATCH / 64, 256, 0, stream>>>(cache_emb, cache_logits, Wt,
                                                 slot_idx, hitm,
                                                 feats_out, logits_out);
}